// Round 7
// baseline (1047.860 us; speedup 1.0000x reference)
//
#include <hip/hip_runtime.h>
#include <cstddef>
#include <cstdint>

#define B_ 64
#define T_ 800
#define D_ 80
#define H_ 128
#define K_ 39
#define BT_ (B_ * T_)   // 51200

// exp2 pre-scale constants: gates are computed as s*pre, s = -log2e (i,f,o)
// or -2*log2e (g), so activations use raw v_exp_f32 with no input multiply.
#define NL2E_  (-1.44269504f)
#define N2L2E_ (-2.88539008f)

typedef _Float16 h2_t  __attribute__((ext_vector_type(2)));
typedef _Float16 f16x8 __attribute__((ext_vector_type(8)));
typedef float    f32x4 __attribute__((ext_vector_type(4)));
typedef uint32_t u32x4 __attribute__((ext_vector_type(4)));

__device__ __forceinline__ float fdot2_(h2_t a, h2_t b, float c) {
#if __has_builtin(__builtin_amdgcn_fdot2)
  return __builtin_amdgcn_fdot2(a, b, c, false);
#else
  return c + (float)a.x * (float)b.x + (float)a.y * (float)b.y;
#endif
}

__device__ __forceinline__ h2_t asH2u_(uint32_t u) { return __builtin_bit_cast(h2_t, u); }

__device__ __forceinline__ float ex2_(float x) {
#if __has_builtin(__builtin_amdgcn_exp2f)
  return __builtin_amdgcn_exp2f(x);
#else
  return __builtin_exp2f(x);
#endif
}
__device__ __forceinline__ float rcpf_(float x) {
#if __has_builtin(__builtin_amdgcn_rcpf)
  return __builtin_amdgcn_rcpf(x);
#else
  return 1.0f / x;
#endif
}
__device__ __forceinline__ float tanhf_(float x) { return 2.0f / (1.0f + __expf(-2.0f * x)) - 1.0f; }

__device__ __forceinline__ float laneb_(float v, int lane) {
  return __builtin_bit_cast(float, __builtin_amdgcn_readlane(__builtin_bit_cast(int, v), lane));
}
__device__ __forceinline__ uint32_t lanebu_(uint32_t v, int lane) {
  return (uint32_t)__builtin_amdgcn_readlane((int)v, lane);
}

// VALU lane-pair swap via DPP quad_perm[1,0,3,2] (0xB1): lane 2k <-> 2k+1.
__device__ __forceinline__ float dppswap1_(float v) {
  return __builtin_bit_cast(float,
    __builtin_amdgcn_mov_dpp(__builtin_bit_cast(int, v), 0xB1, 0xF, 0xF, true));
}

// Generic quad_perm DPP move on a u32 (CTRL: 0xB1=xor1, 0x4E=xor2, 0x1B=xor3).
template<int CTRL>
__device__ __forceinline__ uint32_t dppu_(uint32_t v) {
  return (uint32_t)__builtin_amdgcn_mov_dpp((int)v, CTRL, 0xF, 0xF, true);
}

// LDS-only barrier: waits LDS ops but does NOT drain vmem.
__device__ __forceinline__ void barrier_lds_() {
  asm volatile("s_waitcnt lgkmcnt(0)" ::: "memory");
  __builtin_amdgcn_s_barrier();
}

// lstm lane->gate-rows mapping: wave w, lane L: unit = w*32 + (L>>1),
// role = L&1. role0 owns (i,g) rows, role1 owns (f,o). DPP(1) pairs them.
__device__ __forceinline__ void rows_of_(int tid, int& unit, int& role, int& r0, int& r1) {
  const int w = tid >> 6, L = tid & 63;
  unit = w * 32 + (L >> 1);
  role = L & 1;
  r0 = role * H_ + unit;            // i (role0) or f (role1)
  r1 = 2 * H_ + role * H_ + unit;   // g (role0) or o (role1)
}

// ---------------------------------------------------------------------------
// xw via MFMA 16x16x32 f16, PAIRED output layout, gate rows pre-scaled by
// -log2e (i,f,o) / -2log2e (g) for the exp2 activations. (Unchanged.)
// ---------------------------------------------------------------------------
__global__ __launch_bounds__(256, 1)
void xw_kernel(const float* __restrict__ x,
               const float* __restrict__ Wih_f, const float* __restrict__ Wih_b,
               _Float16* __restrict__ xw)
{
  const int dir = blockIdx.x & 1;
  const int mc  = blockIdx.x >> 1;           // 0..99
  const float* W = dir ? Wih_b : Wih_f;

  const int tid  = threadIdx.x;
  const int w    = tid >> 6;
  const int lane = tid & 63;
  const int lm   = lane & 15;
  const int quad = lane >> 4;
  const int selw = w >> 1;                   // 0: i/f (.x slot), 1: g/o (.y slot)
  const int rolw = w & 1;

  f16x8 Bf[8][3];
  #pragma unroll
  for (int nt = 0; nt < 8; ++nt) {
    const int r = w * 128 + nt * 16 + lm;
    const float fac = (r >= 256 && r < 384) ? N2L2E_ : NL2E_;   // g rows: -2log2e
    #pragma unroll
    for (int kt = 0; kt < 3; ++kt) {
      const int kb = kt * 32 + quad * 8;
      #pragma unroll
      for (int j = 0; j < 8; ++j) {
        const int k = kb + j;
        Bf[nt][kt][j] = (k < D_) ? (_Float16)(fac * W[(size_t)r * D_ + k]) : (_Float16)0.0f;
      }
    }
  }

  __shared__ alignas(16) _Float16 xs[128 * 96];   // 24 KB, K padded to 96
  for (int i = tid; i < 128 * 96; i += 256) xs[i] = (_Float16)0.0f;

  for (int cc = 0; cc < 4; ++cc) {
    const int base = mc * 512 + cc * 128;
    __syncthreads();
    {
      const float4* src = (const float4*)(x + (size_t)base * D_);
      for (int i = tid; i < 128 * D_ / 4; i += 256) {
        float4 v = src[i];
        const int row = i / 20, col = (i % 20) * 4;
        h2_t p0, p1;
        p0.x = (_Float16)v.x; p0.y = (_Float16)v.y;
        p1.x = (_Float16)v.z; p1.y = (_Float16)v.w;
        uint2 pk;
        pk.x = __builtin_bit_cast(uint32_t, p0);
        pk.y = __builtin_bit_cast(uint32_t, p1);
        *(uint2*)&xs[row * 96 + col] = pk;
      }
    }
    __syncthreads();

    #pragma unroll
    for (int mt = 0; mt < 8; ++mt) {
      f16x8 Af[3];
      #pragma unroll
      for (int kt = 0; kt < 3; ++kt)
        Af[kt] = *(const f16x8*)&xs[(mt * 16 + lm) * 96 + kt * 32 + quad * 8];

      f32x4 acc[8];
      #pragma unroll
      for (int nt = 0; nt < 8; ++nt) acc[nt] = (f32x4){0.f, 0.f, 0.f, 0.f};
      #pragma unroll
      for (int kt = 0; kt < 3; ++kt)
        #pragma unroll
        for (int nt = 0; nt < 8; ++nt)
          acc[nt] = __builtin_amdgcn_mfma_f32_16x16x32_f16(Af[kt], Bf[nt][kt], acc[nt], 0, 0, 0);

      #pragma unroll
      for (int nt = 0; nt < 8; ++nt) {
        const int unit = nt * 16 + lm;
        const int ptid = (unit >> 5) * 64 + (unit & 31) * 2 + rolw;
        #pragma unroll
        for (int rg = 0; rg < 4; ++rg) {
          const int bt = base + mt * 16 + quad * 4 + rg;
          xw[((size_t)dir * BT_ + bt) * 512 + ptid * 2 + selw] = (_Float16)acc[nt][rg];
        }
      }
    }
  }
}

// ---------------------------------------------------------------------------
// Recurrent LSTM. R7 change (vs verified R5 structure):
// MAC path = 256 v_fmac_f32 (m07-measured full rate, 2 cyc) instead of 128
// v_dot2_f32_f16 (inferred ~6 cyc from the R4/R5/R6 busy ledger).
//  - Whh weights held f32 in VGPRs (~256 regs; occupancy already 1 wave/SIMD).
//  - h stored f32 in LDS as 4 chunks PADDED to 36 floats (chunk stride 144 B
//    -> the 4 Q-group broadcast addresses occupy 16 disjoint banks: zero
//    conflicts, unlike R6's 128 B stride).
//  - same verified quad_perm DPP chunk exchange (96 DPP/step).
// Everything else identical to R5.
// ---------------------------------------------------------------------------
template<int USE_XW>
__global__ __launch_bounds__(256, 1)
void lstm_kernel(const float* __restrict__ x,
                 const float* __restrict__ Wih_f, const float* __restrict__ Whh_f,
                 const float* __restrict__ bih_f, const float* __restrict__ bhh_f,
                 const float* __restrict__ Wih_b, const float* __restrict__ Whh_b,
                 const float* __restrict__ bih_b, const float* __restrict__ bhh_b,
                 const _Float16* __restrict__ xw,
                 _Float16* __restrict__ hcat)
{
  const int bb  = blockIdx.x & 63;
  const int dir = blockIdx.x >> 6;
  const float* Whh = dir ? Whh_b : Whh_f;
  const float* Wih = dir ? Wih_b : Wih_f;
  const float* bih = dir ? bih_b : bih_f;
  const float* bhh = dir ? bhh_b : bhh_f;

  const int tid  = threadIdx.x;
  const int lane = tid & 63;
  const int Q    = lane & 3;                 // h-chunk this lane reads
  int unit, role, r0, r1; rows_of_(tid, unit, role, r0, r1);
  // row scales: r0 is i/f -> -log2e; r1 is g (role0, -2log2e) or o (role1).
  const float s0 = NL2E_;
  const float s1 = role ? NL2E_ : N2L2E_;
  // qv = (1 + qk2*eb) * rcp(1+eb): role0 tanh(g) (qk2=-1), role1 sig(o) (qk2=0).
  const float qk2 = role ? 0.0f : -1.0f;

  // Whh weights (f32) in Q-PERMUTED order: wq*[r*32+m] pairs with
  // h[32*(Q^r)+m], consumed in round r of the DPP exchange.
  float wq0f[128], wq1f[128];
  #pragma unroll
  for (int r = 0; r < 4; ++r) {
    const int ch = Q ^ r;
    #pragma unroll
    for (int m4 = 0; m4 < 8; ++m4) {
      float4 a = *(const float4*)(Whh + (size_t)r0 * H_ + ch * 32 + m4 * 4);
      float4 d = *(const float4*)(Whh + (size_t)r1 * H_ + ch * 32 + m4 * 4);
      wq0f[r * 32 + m4 * 4 + 0] = s0 * a.x; wq0f[r * 32 + m4 * 4 + 1] = s0 * a.y;
      wq0f[r * 32 + m4 * 4 + 2] = s0 * a.z; wq0f[r * 32 + m4 * 4 + 3] = s0 * a.w;
      wq1f[r * 32 + m4 * 4 + 0] = s1 * d.x; wq1f[r * 32 + m4 * 4 + 1] = s1 * d.y;
      wq1f[r * 32 + m4 * 4 + 2] = s1 * d.z; wq1f[r * 32 + m4 * 4 + 3] = s1 * d.w;
    }
  }
  h2_t wx0[40], wx1[40];
  if (!USE_XW) {
    #pragma unroll
    for (int i = 0; i < 40; ++i) {
      float2 a = *(const float2*)(Wih + (size_t)r0 * D_ + 2 * i);
      float2 d = *(const float2*)(Wih + (size_t)r1 * D_ + 2 * i);
      wx0[i].x = (_Float16)(s0 * a.x); wx0[i].y = (_Float16)(s0 * a.y);
      wx1[i].x = (_Float16)(s1 * d.x); wx1[i].y = (_Float16)(s1 * d.y);
    }
  }
  const float bias0 = s0 * (bih[r0] + bhh[r0]);
  const float bias1 = s1 * (bih[r1] + bhh[r1]);

  // h in f32, 4 chunks of 32 padded to 36 floats (stride 144 B): the four
  // per-Q broadcast addresses of one b128 read map to 16 disjoint banks.
  __shared__ alignas(16) float hch[2][4][36];
  __shared__ uint32_t xs2[2][64];              // fallback x staging

  for (int i = tid; i < 2 * 4 * 36; i += 256) (&hch[0][0][0])[i] = 0.0f;
  if (!USE_XW && tid < 64) { xs2[0][tid] = 0u; xs2[1][tid] = 0u; }
  float c = 0.0f;   // role1 owns cell state of its unit

  const uint32_t* xwdu = (const uint32_t*)xw + ((size_t)dir * BT_ + (size_t)bb * T_) * 256;
  const float*    xb   = x + (size_t)bb * T_ * D_;
  _Float16*       hb   = hcat + (size_t)bb * T_ * (2 * H_) + dir * H_;

  // running pointers/offsets (advance by a constant per step)
  _Float16* hbp = hb + (size_t)(dir ? (T_ - 1) : 0) * (2 * H_);
  const ptrdiff_t hstep = dir ? -(2 * H_) : (2 * H_);
  int xoff = (dir ? (T_ - 3) : 2) * 256 + tid;     // prefetch offset for ttc=2
  const int xstep = dir ? -256 : 256;

  uint32_t xwA = 0u, xwB = 0u;
  h2_t xpend; xpend.x = (_Float16)0.f; xpend.y = (_Float16)0.f;
  {
    const int tq0 = dir ? (T_ - 1) : 0;
    const int tq1 = dir ? (T_ - 2) : 1;
    if (USE_XW) {
      xwA = xwdu[(size_t)tq0 * 256 + tid];
      xwB = xwdu[(size_t)tq1 * 256 + tid];
    } else if (tid < 40) {
      float2 v0 = *(const float2*)(xb + (size_t)tq0 * D_ + 2 * tid);
      h2_t p; p.x = (_Float16)v0.x; p.y = (_Float16)v0.y;
      xs2[0][tid] = __builtin_bit_cast(uint32_t, p);
      float2 v1 = *(const float2*)(xb + (size_t)tq1 * D_ + 2 * tid);
      xpend.x = (_Float16)v1.x; xpend.y = (_Float16)v1.y;
    }
  }
  __syncthreads();

  auto step = [&](int tt, int par, uint32_t& xwreg) {
    float a[4], b[4];
    if (USE_XW) {
      const h2_t xv = asH2u_(xwreg);
      a[0] = bias0 + (float)xv.x;
      b[0] = bias1 + (float)xv.y;
      a[1] = a[2] = a[3] = 0.f; b[1] = b[2] = b[3] = 0.f;
      xwreg = xwdu[xoff];                         // prefetch; consumed 2 steps later
    } else {
      a[0] = bias0; b[0] = bias1;
      a[1] = a[2] = a[3] = 0.f; b[1] = b[2] = b[3] = 0.f;
      if (tid < 40) {
        xs2[par ^ 1][tid] = __builtin_bit_cast(uint32_t, xpend);
        const int ttc = (tt + 2 < T_) ? (tt + 2) : (T_ - 1);
        const int tq2 = dir ? (T_ - 1 - ttc) : ttc;
        float2 v = *(const float2*)(xb + (size_t)tq2 * D_ + 2 * tid);
        xpend.x = (_Float16)v.x; xpend.y = (_Float16)v.y;
      }
      uint32_t xreg = xs2[par][lane];
      #pragma unroll
      for (int j = 0; j < 40; j += 4) {
        h2_t q0 = asH2u_(lanebu_(xreg, j));
        h2_t q1 = asH2u_(lanebu_(xreg, j + 1));
        h2_t q2 = asH2u_(lanebu_(xreg, j + 2));
        h2_t q3 = asH2u_(lanebu_(xreg, j + 3));
        a[0] = fdot2_(wx0[j],     q0, a[0]); b[0] = fdot2_(wx1[j],     q0, b[0]);
        a[1] = fdot2_(wx0[j + 1], q1, a[1]); b[1] = fdot2_(wx1[j + 1], q1, b[1]);
        a[2] = fdot2_(wx0[j + 2], q2, a[2]); b[2] = fdot2_(wx1[j + 2], q2, b[2]);
        a[3] = fdot2_(wx0[j + 3], q3, a[3]); b[3] = fdot2_(wx1[j + 3], q3, b[3]);
      }
    }

    // h @ Whh^T in f32: lane reads ONLY its chunk Q (8 b128, conflict-free
    // padded layout), other chunks arrive via quad_perm DPP (96 DPP);
    // MACs are 256 full-rate v_fmac_f32.
    const u32x4* hq = (const u32x4*)&hch[par][Q][0];
    u32x4 ovr[8];
    #pragma unroll
    for (int g = 0; g < 8; ++g) ovr[g] = hq[g];

    #define HRND_(DAT, RB)                                             \
      _Pragma("unroll")                                                \
      for (int m = 0; m < 32; ++m) {                                   \
        const float hh = __builtin_bit_cast(float, (DAT)[m >> 2][m & 3]); \
        a[m & 3] = fmaf(wq0f[(RB) + m], hh, a[m & 3]);                 \
        b[m & 3] = fmaf(wq1f[(RB) + m], hh, b[m & 3]);                 \
      }

    HRND_(ovr, 0)
    u32x4 cx[8];
    #pragma unroll
    for (int g = 0; g < 8; ++g)
      #pragma unroll
      for (int e = 0; e < 4; ++e) cx[g][e] = dppu_<0xB1>(ovr[g][e]);   // chunk Q^1
    HRND_(cx, 32)
    #pragma unroll
    for (int g = 0; g < 8; ++g)
      #pragma unroll
      for (int e = 0; e < 4; ++e) cx[g][e] = dppu_<0x4E>(ovr[g][e]);   // chunk Q^2
    HRND_(cx, 64)
    #pragma unroll
    for (int g = 0; g < 8; ++g)
      #pragma unroll
      for (int e = 0; e < 4; ++e) cx[g][e] = dppu_<0x1B>(ovr[g][e]);   // chunk Q^3
    HRND_(cx, 96)
    #undef HRND_

    const float ga = (a[0] + a[1]) + (a[2] + a[3]);   // -log2e * (i|f)
    const float gb = (b[0] + b[1]) + (b[2] + b[3]);   // -2log2e*g | -log2e*o

    // activations on exp2-prescaled gates:
    // sg = sig(i|f) = rcp(1+exp2(ga)); qv = tanh(g) (role0) | sig(o) (role1).
    const float ea = ex2_(ga);
    const float sg = rcpf_(1.0f + ea);
    const float gbc = fminf(fmaxf(gb, -34.6f), 34.6f);
    const float eb = ex2_(gbc);
    const float qv = fmaf(qk2, eb, 1.0f) * rcpf_(1.0f + eb);
    const float ex = dppswap1_(sg * qv);      // role1 receives p = sig(i)*tanh(g)
    c = fmaf(sg, c, ex);                      // role1: sig(f)*c + p (role0 benign)
    const float hn = qv * tanhf_(c);          // role1: sig(o)*tanh(c)
    if (role) {
      hch[par ^ 1][unit >> 5][unit & 31] = hn;   // f32 state
      hbp[unit] = (_Float16)hn;                  // async f16 store, never drained
    }
    hbp += hstep;
    if (tt + 3 < T_) xoff += xstep;           // wave-uniform clamp-advance
    barrier_lds_();
  };

  for (int tb = 0; tb < T_; tb += 2) {
    step(tb,     0, xwA);
    step(tb + 1, 1, xwB);
  }
}

// ---------------------------------------------------------------------------
// Emissions via MFMA (unchanged).
// ---------------------------------------------------------------------------
__global__ __launch_bounds__(256, 1)
void emis_kernel(const _Float16* __restrict__ hcat,
                 const float* __restrict__ Wp, const float* __restrict__ bp,
                 float* __restrict__ em)
{
  const int tid  = threadIdx.x;
  const int w    = tid >> 6;
  const int lane = tid & 63;
  const int lm   = lane & 15;
  const int quad = lane >> 4;

  f16x8 Bf[3][8];
  float bias[3];
  #pragma unroll
  for (int nt = 0; nt < 3; ++nt) {
    const int n = nt * 16 + lm;
    const bool valid = n < K_;
    bias[nt] = valid ? bp[n] : 0.0f;
    #pragma unroll
    for (int kt = 0; kt < 8; ++kt) {
      const int kb = kt * 32 + quad * 8;
      #pragma unroll
      for (int j = 0; j < 8; ++j)
        Bf[nt][kt][j] = valid ? (_Float16)Wp[(size_t)n * 256 + kb + j] : (_Float16)0.0f;
    }
  }

  #pragma unroll
  for (int q = 0; q < 4; ++q) {
    const int mt  = blockIdx.x * 16 + w * 4 + q;
    const int bt0 = mt * 16;

    f16x8 Af[8];
    const _Float16* ab = hcat + ((size_t)bt0 + lm) * 256;
    #pragma unroll
    for (int kt = 0; kt < 8; ++kt)
      Af[kt] = *(const f16x8*)(ab + kt * 32 + quad * 8);

    f32x4 acc[3];
    #pragma unroll
    for (int nt = 0; nt < 3; ++nt) acc[nt] = (f32x4){0.f, 0.f, 0.f, 0.f};
    #pragma unroll
    for (int kt = 0; kt < 8; ++kt)
      #pragma unroll
      for (int nt = 0; nt < 3; ++nt)
        acc[nt] = __builtin_amdgcn_mfma_f32_16x16x32_f16(Af[kt], Bf[nt][kt], acc[nt], 0, 0, 0);

    #pragma unroll
    for (int nt = 0; nt < 3; ++nt) {
      const int n = nt * 16 + lm;
      if (n < K_) {
        #pragma unroll
        for (int rg = 0; rg < 4; ++rg) {
          const int row = bt0 + quad * 4 + rg;
          em[(size_t)row * K_ + n] = acc[nt][rg] + bias[nt];
        }
      }
    }
  }
}

// ---------------------------------------------------------------------------
// Fused CRF denominator + numerator (R1 readlane version, unchanged).
// ---------------------------------------------------------------------------
__global__ __launch_bounds__(256)
void crf_dn_kernel(const float* __restrict__ em,
                   const int* __restrict__ labels, const int* __restrict__ lengths,
                   const float* __restrict__ start_t, const float* __restrict__ end_t,
                   const float* __restrict__ trans,
                   float* __restrict__ dn)
{
  const int b    = blockIdx.x;
  const int tid  = threadIdx.x;
  const int wv   = tid >> 6;
  const int lane = tid & 63;
  const int len  = lengths[b];
  const float* emb = em + (size_t)b * T_ * K_;

  __shared__ float s_num[3];
  __shared__ float s_den;

  if (wv == 0) {
    // ---------------- serial denominator, 1 wave ----------------
    float et[K_];
    #pragma unroll
    for (int j = 0; j < K_; ++j)
      et[j] = (lane < K_) ? __expf(trans[j * K_ + lane]) : 0.0f;

    float a0 = (lane < K_) ? (start_t[lane] + emb[lane]) : -1e30f;
    float m = a0;
    #pragma unroll
    for (int off = 32; off > 0; off >>= 1) m = fmaxf(m, __shfl_xor(m, off));
    float v = __expf(a0 - m);           // lanes >= 39 -> 0
    float off_acc = m;

    auto ldc = [&](int t) -> float {
      const int tc = (t < len) ? t : (len - 1);
      return (lane < K_) ? emb[(size_t)tc * K_ + lane] : 0.0f;
    };

    // 8 NAMED pipeline registers — no rotation moves.
    float eA = ldc(1), eB = ldc(2), eC = ldc(3), eD = ldc(4);
    float eE = ldc(5), eF = ldc(6), eG = ldc(7), eH = ldc(8);

    auto stepden = [&](float& ereg, int tt) {
      const float emc = ereg;
      ereg = ldc(tt + 8);               // reload same named reg for tt+8
      if (tt < len) {                   // wave-uniform guard
        const float pv = v;
        float s0 = 0.f, s1 = 0.f, s2 = 0.f, s3 = 0.f;
        #pragma unroll
        for (int j = 0; j < 36; j += 4) {
          s0 = fmaf(laneb_(pv, j),     et[j],     s0);
          s1 = fmaf(laneb_(pv, j + 1), et[j + 1], s1);
          s2 = fmaf(laneb_(pv, j + 2), et[j + 2], s2);
          s3 = fmaf(laneb_(pv, j + 3), et[j + 3], s3);
        }
        s0 = fmaf(laneb_(pv, 36), et[36], s0);
        s1 = fmaf(laneb_(pv, 37), et[37], s1);
        s2 = fmaf(laneb_(pv, 38), et[38], s2);
        v = ((s0 + s1) + (s2 + s3)) * __expf(emc);
        if ((tt & 1) == 0) {            // VALU-only renorm (all terms > 0)
          const float sc = laneb_(v, 0);
          v *= 1.0f / sc;
          off_acc += __logf(sc);
        }
      }
    };

    for (int t = 1; t < len; t += 8) {
      stepden(eA, t);     stepden(eB, t + 1);
      stepden(eC, t + 2); stepden(eD, t + 3);
      stepden(eE, t + 4); stepden(eF, t + 5);
      stepden(eG, t + 6); stepden(eH, t + 7);
    }

    float w = (lane < K_) ? v * __expf(end_t[lane]) : 0.0f;
    #pragma unroll
    for (int off = 32; off > 0; off >>= 1) w += __shfl_xor(w, off);
    if (lane == 0) s_den = off_acc + __logf(w);
  } else {
    // ---------------- parallel numerator, 3 waves ----------------
    const int idx = tid - 64;           // 0..191
    float acc = 0.0f;
    for (int t = 1 + idx; t < len; t += 192) {
      const int lp = labels[b * T_ + t - 1];
      const int lc = labels[b * T_ + t];
      acc += trans[lp * K_ + lc] + emb[(size_t)t * K_ + lc];
    }
    if (tid == 64) {                    // edge terms on one lane
      const int l0 = labels[b * T_];
      const int ll = labels[b * T_ + len - 1];
      acc += start_t[l0] + emb[l0] + end_t[ll];
    }
    #pragma unroll
    for (int off = 32; off > 0; off >>= 1) acc += __shfl_xor(acc, off);
    if (lane == 0) s_num[wv - 1] = acc;
  }
  __syncthreads();
  if (tid == 0) dn[b] = s_den - (s_num[0] + s_num[1] + s_num[2]);
}

// out = mean(dn) over the 64 batch elements (one wave).
__global__ void finalize_kernel(const float* __restrict__ dn, float* __restrict__ out)
{
  const int tid = threadIdx.x;   // 64
  float v = dn[tid];
  #pragma unroll
  for (int off = 32; off > 0; off >>= 1) v += __shfl_down(v, off);
  if (tid == 0) out[0] = v * (1.0f / 64.0f);
}

extern "C" void kernel_launch(void* const* d_in, const int* in_sizes, int n_in,
                              void* d_out, int out_size, void* d_ws, size_t ws_size,
                              hipStream_t stream)
{
  (void)in_sizes; (void)n_in; (void)out_size;
  const float* features = (const float*)d_in[0];
  const int*   lengths  = (const int*)d_in[1];
  const int*   labels   = (const int*)d_in[2];
  const float* Wih_f = (const float*)d_in[3];
  const float* Whh_f = (const float*)d_in[4];
  const float* bih_f = (const float*)d_in[5];
  const float* bhh_f = (const float*)d_in[6];
  const float* Wih_b = (const float*)d_in[7];
  const float* Whh_b = (const float*)d_in[8];
  const float* bih_b = (const float*)d_in[9];
  const float* bhh_b = (const float*)d_in[10];
  const float* Wp      = (const float*)d_in[11];
  const float* bp      = (const float*)d_in[12];
  const float* start_t = (const float*)d_in[13];
  const float* end_t   = (const float*)d_in[14];
  const float* trans   = (const float*)d_in[15];
  float* out = (float*)d_out;

  // ws layout (bytes): hcat f16 [0, 26214400) ; em f32 [26214400, +7987200) ;
  // dn 256 B ; xw f16 [34202112, +104857600) if ws is big enough.
  char* wsc = (char*)d_ws;
  _Float16* hcatH = (_Float16*)wsc;
  float*    em    = (float*)(wsc + 26214400);
  float*    dn    = (float*)(wsc + 26214400 + 7987200);
  _Float16* xwH   = (_Float16*)(wsc + 34202112);
  const bool big  = ws_size >= (size_t)34202112 + 104857600;

  if (big) {
    hipLaunchKernelGGL(xw_kernel, dim3(200), dim3(256), 0, stream,
                       features, Wih_f, Wih_b, xwH);
    hipLaunchKernelGGL((lstm_kernel<1>), dim3(2 * B_), dim3(256), 0, stream,
                       features, Wih_f, Whh_f, bih_f, bhh_f,
                       Wih_b, Whh_b, bih_b, bhh_b, xwH, hcatH);
  } else {
    hipLaunchKernelGGL((lstm_kernel<0>), dim3(2 * B_), dim3(256), 0, stream,
                       features, Wih_f, Whh_f, bih_f, bhh_f,
                       Wih_b, Whh_b, bih_b, bhh_b, xwH, hcatH);
  }
  hipLaunchKernelGGL(emis_kernel, dim3(BT_ / 256), dim3(256), 0, stream,
                     hcatH, Wp, bp, em);
  hipLaunchKernelGGL(crf_dn_kernel, dim3(B_), dim3(256), 0, stream,
                     em, labels, lengths, start_t, end_t, trans, dn);
  hipLaunchKernelGGL(finalize_kernel, dim3(1), dim3(64), 0, stream,
                     dn, out);
}

// Round 8
// 768.964 us; speedup vs baseline: 1.3627x; 1.3627x over previous
//
#include <hip/hip_runtime.h>
#include <cstddef>
#include <cstdint>

#define B_ 64
#define T_ 800
#define D_ 80
#define H_ 128
#define K_ 39
#define BT_ (B_ * T_)   // 51200

// exp2 pre-scale constants: gates are computed as s*pre, s = -log2e (i,f,o)
// or -2*log2e (g), so activations use raw v_exp_f32 with no input multiply.
#define NL2E_  (-1.44269504f)
#define N2L2E_ (-2.88539008f)

typedef _Float16 h2_t  __attribute__((ext_vector_type(2)));
typedef _Float16 f16x8 __attribute__((ext_vector_type(8)));
typedef float    f32x4 __attribute__((ext_vector_type(4)));
typedef uint32_t u32x4 __attribute__((ext_vector_type(4)));

__device__ __forceinline__ float fdot2_(h2_t a, h2_t b, float c) {
#if __has_builtin(__builtin_amdgcn_fdot2)
  return __builtin_amdgcn_fdot2(a, b, c, false);
#else
  return c + (float)a.x * (float)b.x + (float)a.y * (float)b.y;
#endif
}

__device__ __forceinline__ h2_t asH2u_(uint32_t u) { return __builtin_bit_cast(h2_t, u); }

__device__ __forceinline__ float ex2_(float x) {
#if __has_builtin(__builtin_amdgcn_exp2f)
  return __builtin_amdgcn_exp2f(x);
#else
  return __builtin_exp2f(x);
#endif
}
__device__ __forceinline__ float rcpf_(float x) {
#if __has_builtin(__builtin_amdgcn_rcpf)
  return __builtin_amdgcn_rcpf(x);
#else
  return 1.0f / x;
#endif
}
__device__ __forceinline__ float tanhf_(float x) { return 2.0f / (1.0f + __expf(-2.0f * x)) - 1.0f; }

__device__ __forceinline__ float laneb_(float v, int lane) {
  return __builtin_bit_cast(float, __builtin_amdgcn_readlane(__builtin_bit_cast(int, v), lane));
}
__device__ __forceinline__ uint32_t lanebu_(uint32_t v, int lane) {
  return (uint32_t)__builtin_amdgcn_readlane((int)v, lane);
}

// VALU lane-pair swap via DPP quad_perm[1,0,3,2] (0xB1): lane 2k <-> 2k+1.
__device__ __forceinline__ float dppswap1_(float v) {
  return __builtin_bit_cast(float,
    __builtin_amdgcn_mov_dpp(__builtin_bit_cast(int, v), 0xB1, 0xF, 0xF, true));
}

// LDS-only barrier: waits LDS ops but does NOT drain vmem.
__device__ __forceinline__ void barrier_lds_() {
  asm volatile("s_waitcnt lgkmcnt(0)" ::: "memory");
  __builtin_amdgcn_s_barrier();
}

// lstm lane->gate-rows mapping: wave w, lane L: unit = w*32 + (L>>1),
// role = L&1. role0 owns (i,g) rows, role1 owns (f,o). DPP(1) pairs them.
__device__ __forceinline__ void rows_of_(int tid, int& unit, int& role, int& r0, int& r1) {
  const int w = tid >> 6, L = tid & 63;
  unit = w * 32 + (L >> 1);
  role = L & 1;
  r0 = role * H_ + unit;            // i (role0) or f (role1)
  r1 = 2 * H_ + role * H_ + unit;   // g (role0) or o (role1)
}

// ---------------------------------------------------------------------------
// Recurrent LSTM = R4's verified 433us kernel (exp2-prescale, 8 chains,
// uniform-b128 h broadcasts, running offsets) + R8 change: the xw GEMM is a
// PER-BLOCK MFMA PROLOGUE (each block (bb,dir) computes its own 800x512 xw
// slice into ws and then consumes it, L2/L3-warm). The standalone xw_kernel
// and its serialized duration + launch gap are deleted. No cross-block
// dependency: block only reads what it wrote; __syncthreads() drains stores.
// ---------------------------------------------------------------------------
template<int USE_XW>
__global__ __launch_bounds__(256, 1)
void lstm_kernel(const float* __restrict__ x,
                 const float* __restrict__ Wih_f, const float* __restrict__ Whh_f,
                 const float* __restrict__ bih_f, const float* __restrict__ bhh_f,
                 const float* __restrict__ Wih_b, const float* __restrict__ Whh_b,
                 const float* __restrict__ bih_b, const float* __restrict__ bhh_b,
                 _Float16* __restrict__ xw,
                 _Float16* __restrict__ hcat)
{
  const int bb  = blockIdx.x & 63;
  const int dir = blockIdx.x >> 6;
  const float* Whh = dir ? Whh_b : Whh_f;
  const float* Wih = dir ? Wih_b : Wih_f;
  const float* bih = dir ? bih_b : bih_f;
  const float* bhh = dir ? bhh_b : bhh_f;

  const int tid  = threadIdx.x;
  const int lane = tid & 63;

  __shared__ alignas(16) _Float16 hsf[2][H_];      // double-buffered h
  __shared__ uint32_t xs2[2][64];                  // fallback x staging
  __shared__ alignas(16) _Float16 xs[128 * 96];    // prologue staging (24 KB)

  // ---------------- prologue: per-block xw GEMM (USE_XW only) --------------
  if (USE_XW) {
    const int w    = tid >> 6;
    const int lm   = lane & 15;
    const int quad = lane >> 4;
    const int selw = w >> 1;                   // 0: i/f (.x slot), 1: g/o (.y slot)
    const int rolw = w & 1;

    f16x8 Bf[8][3];
    #pragma unroll
    for (int nt = 0; nt < 8; ++nt) {
      const int r = w * 128 + nt * 16 + lm;
      const float fac = (r >= 256 && r < 384) ? N2L2E_ : NL2E_;   // g rows
      #pragma unroll
      for (int kt = 0; kt < 3; ++kt) {
        const int kb = kt * 32 + quad * 8;
        #pragma unroll
        for (int j = 0; j < 8; ++j) {
          const int k = kb + j;
          Bf[nt][kt][j] = (k < D_) ? (_Float16)(fac * Wih[(size_t)r * D_ + k]) : (_Float16)0.0f;
        }
      }
    }

    for (int i = tid; i < 128 * 96; i += 256) xs[i] = (_Float16)0.0f;

    for (int cc = 0; cc < 7; ++cc) {           // 7 chunks of 128 rows (t tail guarded)
      const int base = cc * 128;
      const int nrow = (T_ - base < 128) ? (T_ - base) : 128;
      __syncthreads();
      {
        const float4* src = (const float4*)(x + ((size_t)bb * T_ + base) * D_);
        for (int i = tid; i < nrow * 20; i += 256) {
          float4 v = src[i];
          const int row = i / 20, col = (i % 20) * 4;
          h2_t p0, p1;
          p0.x = (_Float16)v.x; p0.y = (_Float16)v.y;
          p1.x = (_Float16)v.z; p1.y = (_Float16)v.w;
          uint2 pk;
          pk.x = __builtin_bit_cast(uint32_t, p0);
          pk.y = __builtin_bit_cast(uint32_t, p1);
          *(uint2*)&xs[row * 96 + col] = pk;
        }
      }
      __syncthreads();

      #pragma unroll
      for (int mt = 0; mt < 8; ++mt) {
        if (base + mt * 16 >= T_) break;       // whole tile out of range
        f16x8 Af[3];
        #pragma unroll
        for (int kt = 0; kt < 3; ++kt)
          Af[kt] = *(const f16x8*)&xs[(mt * 16 + lm) * 96 + kt * 32 + quad * 8];

        f32x4 acc[8];
        #pragma unroll
        for (int nt = 0; nt < 8; ++nt) acc[nt] = (f32x4){0.f, 0.f, 0.f, 0.f};
        #pragma unroll
        for (int kt = 0; kt < 3; ++kt)
          #pragma unroll
          for (int nt = 0; nt < 8; ++nt)
            acc[nt] = __builtin_amdgcn_mfma_f32_16x16x32_f16(Af[kt], Bf[nt][kt], acc[nt], 0, 0, 0);

        #pragma unroll
        for (int nt = 0; nt < 8; ++nt) {
          const int unit = nt * 16 + lm;
          const int ptid = (unit >> 5) * 64 + (unit & 31) * 2 + rolw;
          #pragma unroll
          for (int rg = 0; rg < 4; ++rg) {
            const int t = base + mt * 16 + quad * 4 + rg;
            if (t < T_)
              xw[((size_t)dir * BT_ + (size_t)bb * T_ + t) * 512 + ptid * 2 + selw]
                = (_Float16)acc[nt][rg];
          }
        }
      }
    }
    __syncthreads();   // compiler drains vmcnt(0) before s_barrier: stores visible
  }

  // ---------------- recurrence (verbatim R4 433us structure) ---------------
  const int Q = lane & 3; (void)Q;
  int unit, role, r0, r1; rows_of_(tid, unit, role, r0, r1);
  const float s0 = NL2E_;
  const float s1 = role ? NL2E_ : N2L2E_;
  const float qk2 = role ? 0.0f : -1.0f;

  h2_t w0[64], w1[64];
  #pragma unroll
  for (int j = 0; j < 64; ++j) {
    float2 a = *(const float2*)(Whh + (size_t)r0 * H_ + 2 * j);
    float2 d = *(const float2*)(Whh + (size_t)r1 * H_ + 2 * j);
    w0[j].x = (_Float16)(s0 * a.x); w0[j].y = (_Float16)(s0 * a.y);
    w1[j].x = (_Float16)(s1 * d.x); w1[j].y = (_Float16)(s1 * d.y);
  }
  h2_t wx0[40], wx1[40];
  if (!USE_XW) {
    #pragma unroll
    for (int i = 0; i < 40; ++i) {
      float2 a = *(const float2*)(Wih + (size_t)r0 * D_ + 2 * i);
      float2 d = *(const float2*)(Wih + (size_t)r1 * D_ + 2 * i);
      wx0[i].x = (_Float16)(s0 * a.x); wx0[i].y = (_Float16)(s0 * a.y);
      wx1[i].x = (_Float16)(s1 * d.x); wx1[i].y = (_Float16)(s1 * d.y);
    }
  }
  const float bias0 = s0 * (bih[r0] + bhh[r0]);
  const float bias1 = s1 * (bih[r1] + bhh[r1]);

  if (tid < H_) hsf[0][tid] = (_Float16)0.0f;
  if (!USE_XW && tid < 64) { xs2[0][tid] = 0u; xs2[1][tid] = 0u; }
  float c = 0.0f;   // role1 owns cell state of its unit

  const uint32_t* xwdu = (const uint32_t*)xw + ((size_t)dir * BT_ + (size_t)bb * T_) * 256;
  const float*    xb   = x + (size_t)bb * T_ * D_;
  _Float16*       hb   = hcat + (size_t)bb * T_ * (2 * H_) + dir * H_;

  _Float16* hbp = hb + (size_t)(dir ? (T_ - 1) : 0) * (2 * H_);
  const ptrdiff_t hstep = dir ? -(2 * H_) : (2 * H_);
  int xoff = (dir ? (T_ - 3) : 2) * 256 + tid;     // prefetch offset for ttc=2
  const int xstep = dir ? -256 : 256;

  uint32_t xwA = 0u, xwB = 0u;
  h2_t xpend; xpend.x = (_Float16)0.f; xpend.y = (_Float16)0.f;
  {
    const int tq0 = dir ? (T_ - 1) : 0;
    const int tq1 = dir ? (T_ - 2) : 1;
    if (USE_XW) {
      xwA = xwdu[(size_t)tq0 * 256 + tid];
      xwB = xwdu[(size_t)tq1 * 256 + tid];
    } else if (tid < 40) {
      float2 v0 = *(const float2*)(xb + (size_t)tq0 * D_ + 2 * tid);
      h2_t p; p.x = (_Float16)v0.x; p.y = (_Float16)v0.y;
      xs2[0][tid] = __builtin_bit_cast(uint32_t, p);
      float2 v1 = *(const float2*)(xb + (size_t)tq1 * D_ + 2 * tid);
      xpend.x = (_Float16)v1.x; xpend.y = (_Float16)v1.y;
    }
  }
  __syncthreads();

  auto step = [&](int tt, int par, uint32_t& xwreg) {
    float a0, a1, a2, a3, b0, b1, b2, b3;
    if (USE_XW) {
      const h2_t xv = asH2u_(xwreg);
      a0 = bias0 + (float)xv.x;
      b0 = bias1 + (float)xv.y;
      a1 = a2 = a3 = 0.f; b1 = b2 = b3 = 0.f;
      xwreg = xwdu[xoff];                         // prefetch; consumed 2 steps later
    } else {
      a0 = bias0; b0 = bias1;
      a1 = a2 = a3 = 0.f; b1 = b2 = b3 = 0.f;
      if (tid < 40) {
        xs2[par ^ 1][tid] = __builtin_bit_cast(uint32_t, xpend);
        const int ttc = (tt + 2 < T_) ? (tt + 2) : (T_ - 1);
        const int tq2 = dir ? (T_ - 1 - ttc) : ttc;
        float2 v = *(const float2*)(xb + (size_t)tq2 * D_ + 2 * tid);
        xpend.x = (_Float16)v.x; xpend.y = (_Float16)v.y;
      }
      uint32_t xreg = xs2[par][lane];
      #pragma unroll
      for (int j = 0; j < 40; j += 4) {
        h2_t q0 = asH2u_(lanebu_(xreg, j));
        h2_t q1 = asH2u_(lanebu_(xreg, j + 1));
        h2_t q2 = asH2u_(lanebu_(xreg, j + 2));
        h2_t q3 = asH2u_(lanebu_(xreg, j + 3));
        a0 = fdot2_(wx0[j],     q0, a0); b0 = fdot2_(wx1[j],     q0, b0);
        a1 = fdot2_(wx0[j + 1], q1, a1); b1 = fdot2_(wx1[j + 1], q1, b1);
        a2 = fdot2_(wx0[j + 2], q2, a2); b2 = fdot2_(wx1[j + 2], q2, b2);
        a3 = fdot2_(wx0[j + 3], q3, a3); b3 = fdot2_(wx1[j + 3], q3, b3);
      }
    }

    // h @ Whh^T via uniform-address LDS broadcasts, interleaved (compiler
    // pipelines with partial lgkmcnt waits). 8 chains, depth 16.
    const u32x4* hq = (const u32x4*)hsf[par];
    #pragma unroll
    for (int g = 0; g < 16; ++g) {
      const u32x4 hv = hq[g];
      a0 = fdot2_(w0[4 * g + 0], asH2u_(hv[0]), a0);
      b0 = fdot2_(w1[4 * g + 0], asH2u_(hv[0]), b0);
      a1 = fdot2_(w0[4 * g + 1], asH2u_(hv[1]), a1);
      b1 = fdot2_(w1[4 * g + 1], asH2u_(hv[1]), b1);
      a2 = fdot2_(w0[4 * g + 2], asH2u_(hv[2]), a2);
      b2 = fdot2_(w1[4 * g + 2], asH2u_(hv[2]), b2);
      a3 = fdot2_(w0[4 * g + 3], asH2u_(hv[3]), a3);
      b3 = fdot2_(w1[4 * g + 3], asH2u_(hv[3]), b3);
    }
    const float ga = (a0 + a1) + (a2 + a3);   // -log2e * (i|f)
    const float gb = (b0 + b1) + (b2 + b3);   // -2log2e*g | -log2e*o

    const float ea = ex2_(ga);
    const float sg = rcpf_(1.0f + ea);
    const float gbc = fminf(fmaxf(gb, -34.6f), 34.6f);
    const float eb = ex2_(gbc);
    const float qv = fmaf(qk2, eb, 1.0f) * rcpf_(1.0f + eb);
    const float ex = dppswap1_(sg * qv);      // role1 receives p = sig(i)*tanh(g)
    c = fmaf(sg, c, ex);                      // role1: sig(f)*c + p (role0 benign)
    const float hn = qv * tanhf_(c);          // role1: sig(o)*tanh(c)
    if (role) {
      hsf[par ^ 1][unit] = (_Float16)hn;
      hbp[unit] = (_Float16)hn;               // async store, never drained
    }
    hbp += hstep;
    if (tt + 3 < T_) xoff += xstep;           // wave-uniform clamp-advance
    barrier_lds_();
  };

  for (int tb = 0; tb < T_; tb += 2) {
    step(tb,     0, xwA);
    step(tb + 1, 1, xwB);
  }
}

// ---------------------------------------------------------------------------
// Emissions via MFMA (unchanged).
// ---------------------------------------------------------------------------
__global__ __launch_bounds__(256, 1)
void emis_kernel(const _Float16* __restrict__ hcat,
                 const float* __restrict__ Wp, const float* __restrict__ bp,
                 float* __restrict__ em)
{
  const int tid  = threadIdx.x;
  const int w    = tid >> 6;
  const int lane = tid & 63;
  const int lm   = lane & 15;
  const int quad = lane >> 4;

  f16x8 Bf[3][8];
  float bias[3];
  #pragma unroll
  for (int nt = 0; nt < 3; ++nt) {
    const int n = nt * 16 + lm;
    const bool valid = n < K_;
    bias[nt] = valid ? bp[n] : 0.0f;
    #pragma unroll
    for (int kt = 0; kt < 8; ++kt) {
      const int kb = kt * 32 + quad * 8;
      #pragma unroll
      for (int j = 0; j < 8; ++j)
        Bf[nt][kt][j] = valid ? (_Float16)Wp[(size_t)n * 256 + kb + j] : (_Float16)0.0f;
    }
  }

  #pragma unroll
  for (int q = 0; q < 4; ++q) {
    const int mt  = blockIdx.x * 16 + w * 4 + q;
    const int bt0 = mt * 16;

    f16x8 Af[8];
    const _Float16* ab = hcat + ((size_t)bt0 + lm) * 256;
    #pragma unroll
    for (int kt = 0; kt < 8; ++kt)
      Af[kt] = *(const f16x8*)(ab + kt * 32 + quad * 8);

    f32x4 acc[3];
    #pragma unroll
    for (int nt = 0; nt < 3; ++nt) acc[nt] = (f32x4){0.f, 0.f, 0.f, 0.f};
    #pragma unroll
    for (int kt = 0; kt < 8; ++kt)
      #pragma unroll
      for (int nt = 0; nt < 3; ++nt)
        acc[nt] = __builtin_amdgcn_mfma_f32_16x16x32_f16(Af[kt], Bf[nt][kt], acc[nt], 0, 0, 0);

    #pragma unroll
    for (int nt = 0; nt < 3; ++nt) {
      const int n = nt * 16 + lm;
      if (n < K_) {
        #pragma unroll
        for (int rg = 0; rg < 4; ++rg) {
          const int row = bt0 + quad * 4 + rg;
          em[(size_t)row * K_ + n] = acc[nt][rg] + bias[nt];
        }
      }
    }
  }
}

// ---------------------------------------------------------------------------
// Fused CRF denominator + numerator (R1 readlane version; R8: renorm every
// 4th step instead of 2nd — growth <= ~3e4/step, 4 steps ~ 6e18 << f32 max).
// ---------------------------------------------------------------------------
__global__ __launch_bounds__(256)
void crf_dn_kernel(const float* __restrict__ em,
                   const int* __restrict__ labels, const int* __restrict__ lengths,
                   const float* __restrict__ start_t, const float* __restrict__ end_t,
                   const float* __restrict__ trans,
                   float* __restrict__ dn)
{
  const int b    = blockIdx.x;
  const int tid  = threadIdx.x;
  const int wv   = tid >> 6;
  const int lane = tid & 63;
  const int len  = lengths[b];
  const float* emb = em + (size_t)b * T_ * K_;

  __shared__ float s_num[3];
  __shared__ float s_den;

  if (wv == 0) {
    // ---------------- serial denominator, 1 wave ----------------
    float et[K_];
    #pragma unroll
    for (int j = 0; j < K_; ++j)
      et[j] = (lane < K_) ? __expf(trans[j * K_ + lane]) : 0.0f;

    float a0 = (lane < K_) ? (start_t[lane] + emb[lane]) : -1e30f;
    float m = a0;
    #pragma unroll
    for (int off = 32; off > 0; off >>= 1) m = fmaxf(m, __shfl_xor(m, off));
    float v = __expf(a0 - m);           // lanes >= 39 -> 0
    float off_acc = m;

    auto ldc = [&](int t) -> float {
      const int tc = (t < len) ? t : (len - 1);
      return (lane < K_) ? emb[(size_t)tc * K_ + lane] : 0.0f;
    };

    // 8 NAMED pipeline registers — no rotation moves.
    float eA = ldc(1), eB = ldc(2), eC = ldc(3), eD = ldc(4);
    float eE = ldc(5), eF = ldc(6), eG = ldc(7), eH = ldc(8);

    auto stepden = [&](float& ereg, int tt) {
      const float emc = ereg;
      ereg = ldc(tt + 8);               // reload same named reg for tt+8
      if (tt < len) {                   // wave-uniform guard
        const float pv = v;
        float s0 = 0.f, s1 = 0.f, s2 = 0.f, s3 = 0.f;
        #pragma unroll
        for (int j = 0; j < 36; j += 4) {
          s0 = fmaf(laneb_(pv, j),     et[j],     s0);
          s1 = fmaf(laneb_(pv, j + 1), et[j + 1], s1);
          s2 = fmaf(laneb_(pv, j + 2), et[j + 2], s2);
          s3 = fmaf(laneb_(pv, j + 3), et[j + 3], s3);
        }
        s0 = fmaf(laneb_(pv, 36), et[36], s0);
        s1 = fmaf(laneb_(pv, 37), et[37], s1);
        s2 = fmaf(laneb_(pv, 38), et[38], s2);
        v = ((s0 + s1) + (s2 + s3)) * __expf(emc);
        if ((tt & 3) == 0) {            // VALU-only renorm (all terms > 0)
          const float sc = laneb_(v, 0);
          v *= 1.0f / sc;
          off_acc += __logf(sc);
        }
      }
    };

    for (int t = 1; t < len; t += 8) {
      stepden(eA, t);     stepden(eB, t + 1);
      stepden(eC, t + 2); stepden(eD, t + 3);
      stepden(eE, t + 4); stepden(eF, t + 5);
      stepden(eG, t + 6); stepden(eH, t + 7);
    }

    float w = (lane < K_) ? v * __expf(end_t[lane]) : 0.0f;
    #pragma unroll
    for (int off = 32; off > 0; off >>= 1) w += __shfl_xor(w, off);
    if (lane == 0) s_den = off_acc + __logf(w);
  } else {
    // ---------------- parallel numerator, 3 waves ----------------
    const int idx = tid - 64;           // 0..191
    float acc = 0.0f;
    for (int t = 1 + idx; t < len; t += 192) {
      const int lp = labels[b * T_ + t - 1];
      const int lc = labels[b * T_ + t];
      acc += trans[lp * K_ + lc] + emb[(size_t)t * K_ + lc];
    }
    if (tid == 64) {                    // edge terms on one lane
      const int l0 = labels[b * T_];
      const int ll = labels[b * T_ + len - 1];
      acc += start_t[l0] + emb[l0] + end_t[ll];
    }
    #pragma unroll
    for (int off = 32; off > 0; off >>= 1) acc += __shfl_xor(acc, off);
    if (lane == 0) s_num[wv - 1] = acc;
  }
  __syncthreads();
  if (tid == 0) dn[b] = s_den - (s_num[0] + s_num[1] + s_num[2]);
}

// out = mean(dn) over the 64 batch elements (one wave).
__global__ void finalize_kernel(const float* __restrict__ dn, float* __restrict__ out)
{
  const int tid = threadIdx.x;   // 64
  float v = dn[tid];
  #pragma unroll
  for (int off = 32; off > 0; off >>= 1) v += __shfl_down(v, off);
  if (tid == 0) out[0] = v * (1.0f / 64.0f);
}

extern "C" void kernel_launch(void* const* d_in, const int* in_sizes, int n_in,
                              void* d_out, int out_size, void* d_ws, size_t ws_size,
                              hipStream_t stream)
{
  (void)in_sizes; (void)n_in; (void)out_size;
  const float* features = (const float*)d_in[0];
  const int*   lengths  = (const int*)d_in[1];
  const int*   labels   = (const int*)d_in[2];
  const float* Wih_f = (const float*)d_in[3];
  const float* Whh_f = (const float*)d_in[4];
  const float* bih_f = (const float*)d_in[5];
  const float* bhh_f = (const float*)d_in[6];
  const float* Wih_b = (const float*)d_in[7];
  const float* Whh_b = (const float*)d_in[8];
  const float* bih_b = (const float*)d_in[9];
  const float* bhh_b = (const float*)d_in[10];
  const float* Wp      = (const float*)d_in[11];
  const float* bp      = (const float*)d_in[12];
  const float* start_t = (const float*)d_in[13];
  const float* end_t   = (const float*)d_in[14];
  const float* trans   = (const float*)d_in[15];
  float* out = (float*)d_out;

  // ws layout (bytes): hcat f16 [0, 26214400) ; em f32 [26214400, +7987200) ;
  // dn 256 B ; xw f16 [34202112, +104857600) if ws is big enough.
  char* wsc = (char*)d_ws;
  _Float16* hcatH = (_Float16*)wsc;
  float*    em    = (float*)(wsc + 26214400);
  float*    dn    = (float*)(wsc + 26214400 + 7987200);
  _Float16* xwH   = (_Float16*)(wsc + 34202112);
  const bool big  = ws_size >= (size_t)34202112 + 104857600;

  if (big) {
    hipLaunchKernelGGL((lstm_kernel<1>), dim3(2 * B_), dim3(256), 0, stream,
                       features, Wih_f, Whh_f, bih_f, bhh_f,
                       Wih_b, Whh_b, bih_b, bhh_b, xwH, hcatH);
  } else {
    hipLaunchKernelGGL((lstm_kernel<0>), dim3(2 * B_), dim3(256), 0, stream,
                       features, Wih_f, Whh_f, bih_f, bhh_f,
                       Wih_b, Whh_b, bih_b, bhh_b, xwH, hcatH);
  }
  hipLaunchKernelGGL(emis_kernel, dim3(BT_ / 256), dim3(256), 0, stream,
                     hcatH, Wp, bp, em);
  hipLaunchKernelGGL(crf_dn_kernel, dim3(B_), dim3(256), 0, stream,
                     em, labels, lengths, start_t, end_t, trans, dn);
  hipLaunchKernelGGL(finalize_kernel, dim3(1), dim3(64), 0, stream,
                     dn, out);
}